// Round 2
// baseline (486.416 us; speedup 1.0000x reference)
//
#include <hip/hip_runtime.h>
#include <math.h>

// B=262144 rows, C=16 clusters, F=16 features, H=12 hidden, HH=12 head-hidden
#define NB      262144
#define NC      16
#define NF      16
#define NH      12
#define NHH     12
#define THREADS 256
#define BX      (NB / THREADS)   // 1024 row-blocks
#define GY      4                // cluster splits
#define CPB     (NC / GY)        // 4 clusters per block

__device__ __forceinline__ float sigmoid_fast(float z) {
    float e = __expf(-z);
    return __builtin_amdgcn_rcpf(1.0f + e);
}

// Main pass: thread = row; block column by handles clusters [by*4, by*4+4).
// Weights are wave-uniform (scalar pipe). x loads double-buffered one cluster
// ahead. Reductions deferred to kernel end (4 register accumulators).
__global__ __launch_bounds__(THREADS, 8) void ae_main(
    const float* __restrict__ x,     // [B][256]
    const float* __restrict__ We,    // [C][H][F]
    const float* __restrict__ be,    // [C][H]
    const float* __restrict__ Wd,    // [C][F][H]
    const float* __restrict__ bd,    // [C][F]
    float* __restrict__ partials)    // [GY][BX][CPB]
{
    const int tid  = threadIdx.x;
    const int lane = tid & 63;
    const int wave = tid >> 6;
    const int c0   = blockIdx.y * CPB;
    const size_t b = (size_t)blockIdx.x * THREADS + tid;

    const float4* xp = reinterpret_cast<const float4*>(x + b * (NC * NF) + (size_t)c0 * NF);

    float acc[CPB];
    float4 buf0 = xp[0], buf1 = xp[1], buf2 = xp[2], buf3 = xp[3];

    #pragma unroll
    for (int j = 0; j < CPB; ++j) {
        float xc[NF];
        xc[0]=buf0.x; xc[1]=buf0.y; xc[2]=buf0.z; xc[3]=buf0.w;
        xc[4]=buf1.x; xc[5]=buf1.y; xc[6]=buf1.z; xc[7]=buf1.w;
        xc[8]=buf2.x; xc[9]=buf2.y; xc[10]=buf2.z; xc[11]=buf2.w;
        xc[12]=buf3.x; xc[13]=buf3.y; xc[14]=buf3.z; xc[15]=buf3.w;
        if (j + 1 < CPB) {   // prefetch next cluster while computing this one
            buf0 = xp[4*(j+1)+0]; buf1 = xp[4*(j+1)+1];
            buf2 = xp[4*(j+1)+2]; buf3 = xp[4*(j+1)+3];
        }

        const int c = c0 + j;
        const float* wec = We + c * (NH * NF);   // wave-uniform -> s_load
        const float* bec = be + c * NH;
        float h[NH];
        #pragma unroll
        for (int hh = 0; hh < NH; ++hh) {
            float z = bec[hh];
            #pragma unroll
            for (int f = 0; f < NF; ++f)
                z = fmaf(xc[f], wec[hh * NF + f], z);
            h[hh] = sigmoid_fast(z);
        }

        const float* wdc = Wd + c * (NF * NH);
        const float* bdc = bd + c * NF;
        float lsum = 0.0f;
        #pragma unroll
        for (int f = 0; f < NF; ++f) {
            float z = bdc[f];
            #pragma unroll
            for (int hh = 0; hh < NH; ++hh)
                z = fmaf(h[hh], wdc[f * NH + hh], z);
            float r = sigmoid_fast(z);
            float d = r - xc[f];
            lsum = fmaf(d, d, lsum);
        }
        acc[j] = lsum;
    }

    // end-of-kernel reduction: 4 clusters x butterfly over 64 lanes
    __shared__ float wred[CPB][4];
    #pragma unroll
    for (int j = 0; j < CPB; ++j) {
        float v = acc[j];
        #pragma unroll
        for (int off = 32; off > 0; off >>= 1)
            v += __shfl_down(v, off, 64);
        if (lane == 0) wred[j][wave] = v;
    }
    __syncthreads();
    if (tid < CPB) {
        float s = wred[tid][0] + wred[tid][1] + wred[tid][2] + wred[tid][3];
        partials[((size_t)blockIdx.y * BX + blockIdx.x) * CPB + tid] = s;
    }
}

// Final pass: reduce partials -> per-cluster loss -> tails -> head.
__global__ __launch_bounds__(THREADS) void ae_final(
    const float* __restrict__ partials,  // [GY][BX][CPB]
    const float* __restrict__ He,        // [HH][C]
    const float* __restrict__ hbe,       // [HH]
    const float* __restrict__ Hd,        // [C][HH]
    const float* __restrict__ hbd,       // [C]
    float* __restrict__ out)             // [0..15]=head_out, [16..31]=tails
{
    __shared__ float red[NC][17];
    __shared__ float tails_s[NC];
    __shared__ float h2_s[NHH];

    const int tid = threadIdx.x;
    const int c = tid & 15;              // cluster
    const int g = tid >> 4;              // 16 reduction groups
    const int by = c >> 2, jj = c & 3;

    float s = 0.0f;
    for (int bx = g; bx < BX; bx += 16)
        s += partials[((size_t)by * BX + bx) * CPB + jj];
    red[c][g] = s;
    __syncthreads();

    if (tid < NC) {
        float t = 0.0f;
        #pragma unroll
        for (int g2 = 0; g2 < 16; ++g2) t += red[tid][g2];
        float loss = sqrtf(t * (1.0f / 4194304.0f));   // mean over B*F
        if (loss == 0.0f) loss = 0.01f;
        tails_s[tid] = loss;
        out[16 + tid] = loss;
    }
    __syncthreads();

    if (tid < NHH) {
        float z = hbe[tid];
        #pragma unroll
        for (int cc = 0; cc < NC; ++cc)
            z = fmaf(He[tid * NC + cc], tails_s[cc], z);
        h2_s[tid] = 1.0f / (1.0f + __expf(-z));
    }
    __syncthreads();

    if (tid < NC) {
        float z = hbd[tid];
        #pragma unroll
        for (int j = 0; j < NHH; ++j)
            z = fmaf(Hd[tid * NHH + j], h2_s[j], z);
        out[tid] = 1.0f / (1.0f + __expf(-z));
    }
}

extern "C" void kernel_launch(void* const* d_in, const int* in_sizes, int n_in,
                              void* d_out, int out_size, void* d_ws, size_t ws_size,
                              hipStream_t stream) {
    // setup_inputs order: x, We, be, Wd, bd, He, hbe, Hd, hbd, cluster_idx
    const float* x   = (const float*)d_in[0];
    const float* We  = (const float*)d_in[1];
    const float* be  = (const float*)d_in[2];
    const float* Wd  = (const float*)d_in[3];
    const float* bd  = (const float*)d_in[4];
    const float* He  = (const float*)d_in[5];
    const float* hbe = (const float*)d_in[6];
    const float* Hd  = (const float*)d_in[7];
    const float* hbd = (const float*)d_in[8];
    // d_in[9] = cluster_idx: arange -> identity gather, folded in.

    float* out      = (float*)d_out;
    float* partials = (float*)d_ws;      // GY*BX*CPB*4 = 64 KB

    dim3 grid(BX, GY);
    ae_main<<<grid, THREADS, 0, stream>>>(x, We, be, Wd, bd, partials);
    ae_final<<<1, THREADS, 0, stream>>>(partials, He, hbe, Hd, hbd, out);
}

// Round 3
// 452.720 us; speedup vs baseline: 1.0744x; 1.0744x over previous
//
#include <hip/hip_runtime.h>
#include <math.h>

// B=262144 rows, C=16 clusters, F=16 features, H=12 hidden, HH=12 head-hidden
#define NB      262144
#define NC      16
#define NF      16
#define NH      12
#define NHH     12
#define THREADS 256
#define BX      (NB / THREADS)   // 1024 row-blocks

__device__ __forceinline__ float sigmoid_fast(float z) {
    float e = __expf(-z);
    return __builtin_amdgcn_rcpf(1.0f + e);
}

// Main pass: one thread per row, all 16 clusters per thread (1 KB contiguous
// read per thread -> every cache line fully consumed, no duplicate fetch).
// Rolling register prefetch: cluster c+1's 4 float4 loads are issued before
// cluster c's ~450-instr compute -> ~900 cycles of latency hiding per iter.
// No min-wave __launch_bounds__: grid (1024 blocks = 4 waves/SIMD) is the
// occupancy cap anyway, so VGPR<=128 is free — avoids R2's scratch spills.
__global__ __launch_bounds__(THREADS) void ae_main(
    const float* __restrict__ x,     // [B][256]
    const float* __restrict__ We,    // [C][H][F]
    const float* __restrict__ be,    // [C][H]
    const float* __restrict__ Wd,    // [C][F][H]
    const float* __restrict__ bd,    // [C][F]
    float* __restrict__ partials)    // [BX][NC]
{
    const int tid  = threadIdx.x;
    const int lane = tid & 63;
    const int wave = tid >> 6;
    const size_t b = (size_t)blockIdx.x * THREADS + tid;

    __shared__ float wred[NC][4];

    const float4* xp = reinterpret_cast<const float4*>(x + b * (NC * NF));

    // prime the pipeline with cluster 0
    float4 b0 = xp[0], b1 = xp[1], b2 = xp[2], b3 = xp[3];

    #pragma unroll 1
    for (int c = 0; c < NC; ++c) {
        float xc[NF];
        xc[0]=b0.x;  xc[1]=b0.y;  xc[2]=b0.z;  xc[3]=b0.w;
        xc[4]=b1.x;  xc[5]=b1.y;  xc[6]=b1.z;  xc[7]=b1.w;
        xc[8]=b2.x;  xc[9]=b2.y;  xc[10]=b2.z; xc[11]=b2.w;
        xc[12]=b3.x; xc[13]=b3.y; xc[14]=b3.z; xc[15]=b3.w;

        // prefetch next cluster (clamped: last iter re-reads own cluster,
        // avoids 64-B OOB read past end of x for the final row)
        const int cn = (c + 1 < NC) ? (c + 1) : c;
        b0 = xp[4*cn+0]; b1 = xp[4*cn+1]; b2 = xp[4*cn+2]; b3 = xp[4*cn+3];

        // ---- encoder: h = sigmoid(xc . We[c]^T + be[c]) (weights scalar) ----
        const float* wec = We + c * (NH * NF);
        const float* bec = be + c * NH;
        float h[NH];
        #pragma unroll
        for (int hh = 0; hh < NH; ++hh) {
            float z = bec[hh];
            #pragma unroll
            for (int f = 0; f < NF; ++f)
                z = fmaf(xc[f], wec[hh * NF + f], z);
            h[hh] = sigmoid_fast(z);
        }

        // ---- decoder + squared error ----
        const float* wdc = Wd + c * (NF * NH);
        const float* bdc = bd + c * NF;
        float lsum = 0.0f;
        #pragma unroll
        for (int f = 0; f < NF; ++f) {
            float z = bdc[f];
            #pragma unroll
            for (int hh = 0; hh < NH; ++hh)
                z = fmaf(h[hh], wdc[f * NH + hh], z);
            float r = sigmoid_fast(z);
            float d = r - xc[f];
            lsum = fmaf(d, d, lsum);
        }

        // immediate wave reduction (frees per-cluster acc registers)
        #pragma unroll
        for (int off = 32; off > 0; off >>= 1)
            lsum += __shfl_down(lsum, off, 64);
        if (lane == 0) wred[c][wave] = lsum;
    }

    __syncthreads();
    if (tid < NC) {
        float s = wred[tid][0] + wred[tid][1] + wred[tid][2] + wred[tid][3];
        partials[(size_t)blockIdx.x * NC + tid] = s;
    }
}

// Final pass: reduce per-block partials -> per-cluster loss -> tails -> head.
__global__ __launch_bounds__(1024) void ae_final(
    const float* __restrict__ partials,  // [BX][NC]
    const float* __restrict__ He,        // [HH][C]
    const float* __restrict__ hbe,       // [HH]
    const float* __restrict__ Hd,        // [C][HH]
    const float* __restrict__ hbd,       // [C]
    float* __restrict__ out)             // [0..15]=head_out, [16..31]=tails
{
    __shared__ float red[NC][65];
    __shared__ float tails_s[NC];
    __shared__ float h2_s[NHH];

    const int tid = threadIdx.x;
    const int c = tid & 15;              // cluster
    const int g = tid >> 4;              // 64 reduction groups

    // fully-coalesced: consecutive tids read consecutive addresses
    float s = 0.0f;
    for (int bx = g; bx < BX; bx += 64)
        s += partials[(size_t)bx * NC + c];
    red[c][g] = s;
    __syncthreads();

    if (tid < NC) {
        float t = 0.0f;
        #pragma unroll
        for (int g2 = 0; g2 < 64; ++g2) t += red[tid][g2];
        float loss = sqrtf(t * (1.0f / 4194304.0f));   // mean over B*F
        if (loss == 0.0f) loss = 0.01f;
        tails_s[tid] = loss;
        out[16 + tid] = loss;
    }
    __syncthreads();

    if (tid < NHH) {
        float z = hbe[tid];
        #pragma unroll
        for (int cc = 0; cc < NC; ++cc)
            z = fmaf(He[tid * NC + cc], tails_s[cc], z);
        h2_s[tid] = 1.0f / (1.0f + __expf(-z));
    }
    __syncthreads();

    if (tid < NC) {
        float z = hbd[tid];
        #pragma unroll
        for (int j = 0; j < NHH; ++j)
            z = fmaf(Hd[tid * NHH + j], h2_s[j], z);
        out[tid] = 1.0f / (1.0f + __expf(-z));
    }
}

extern "C" void kernel_launch(void* const* d_in, const int* in_sizes, int n_in,
                              void* d_out, int out_size, void* d_ws, size_t ws_size,
                              hipStream_t stream) {
    // setup_inputs order: x, We, be, Wd, bd, He, hbe, Hd, hbd, cluster_idx
    const float* x   = (const float*)d_in[0];
    const float* We  = (const float*)d_in[1];
    const float* be  = (const float*)d_in[2];
    const float* Wd  = (const float*)d_in[3];
    const float* bd  = (const float*)d_in[4];
    const float* He  = (const float*)d_in[5];
    const float* hbe = (const float*)d_in[6];
    const float* Hd  = (const float*)d_in[7];
    const float* hbd = (const float*)d_in[8];
    // d_in[9] = cluster_idx: arange -> identity gather, folded in.

    float* out      = (float*)d_out;
    float* partials = (float*)d_ws;      // BX*NC*4 = 64 KB

    ae_main<<<BX, THREADS, 0, stream>>>(x, We, be, Wd, bd, partials);
    ae_final<<<1, 1024, 0, stream>>>(partials, He, hbe, Hd, hbd, out);
}

// Round 4
// 398.628 us; speedup vs baseline: 1.2202x; 1.1357x over previous
//
#include <hip/hip_runtime.h>
#include <math.h>

// B=262144 rows, C=16 clusters, F=16 features, H=12 hidden, HH=12 head-hidden
#define NB      262144
#define NC      16
#define NF      16
#define NH      12
#define NHH     12
#define THREADS 256
#define BX      (NB / THREADS)   // 1024 row-blocks
#define NPAIR   8                // cluster pairs per row
#define CPP     2                // clusters per pair

__device__ __forceinline__ float sigmoid_fast(float z) {
    float e = __expf(-z);
    return __builtin_amdgcn_rcpf(1.0f + e);
}

// Block (bx, py) handles rows [bx*256, bx*256+256) x clusters {2py, 2py+1}.
// Why pairs: per-block weight set = 2*(192+192+28)*4B = 3.3 KB -> stays hot in
// the 16 KB scalar cache across the block's lifetime (R3's 26 KB/iteration
// weight stream thrashed SQC -> ~1000 stall cyc/cluster on s_load lgkm waits).
// A pair slice = bytes [p*128, p*128+128) of each 1 KB row = exactly one
// 128-B cache line per row -> zero cross-block overfetch.
__global__ __launch_bounds__(THREADS) void ae_main(
    const float* __restrict__ x,     // [B][256]
    const float* __restrict__ We,    // [C][H][F]
    const float* __restrict__ be,    // [C][H]
    const float* __restrict__ Wd,    // [C][F][H]
    const float* __restrict__ bd,    // [C][F]
    float* __restrict__ partials)    // [NPAIR][BX][CPP]
{
    const int tid  = threadIdx.x;
    const int lane = tid & 63;
    const int wave = tid >> 6;
    const int c0   = blockIdx.y * CPP;
    const size_t b = (size_t)blockIdx.x * THREADS + tid;

    __shared__ float wred[CPP][4];

    const float4* xp = reinterpret_cast<const float4*>(
        x + b * (NC * NF) + (size_t)c0 * NF);

    // all 128 B for the pair issued up-front (8 dwordx4 in flight)
    float4 v[2 * 4];
    #pragma unroll
    for (int k = 0; k < 8; ++k) v[k] = xp[k];

    #pragma unroll
    for (int j = 0; j < CPP; ++j) {
        float xc[NF];
        #pragma unroll
        for (int k = 0; k < 4; ++k) {
            xc[4*k+0] = v[4*j+k].x; xc[4*k+1] = v[4*j+k].y;
            xc[4*k+2] = v[4*j+k].z; xc[4*k+3] = v[4*j+k].w;
        }

        const int c = c0 + j;
        // ---- encoder: h = sigmoid(xc . We[c]^T + be[c]) (weights scalar) ----
        const float* wec = We + c * (NH * NF);
        const float* bec = be + c * NH;
        float h[NH];
        #pragma unroll
        for (int hh = 0; hh < NH; ++hh) {
            float z = bec[hh];
            #pragma unroll
            for (int f = 0; f < NF; ++f)
                z = fmaf(xc[f], wec[hh * NF + f], z);
            h[hh] = sigmoid_fast(z);
        }

        // ---- decoder + squared error ----
        const float* wdc = Wd + c * (NF * NH);
        const float* bdc = bd + c * NF;
        float lsum = 0.0f;
        #pragma unroll
        for (int f = 0; f < NF; ++f) {
            float z = bdc[f];
            #pragma unroll
            for (int hh = 0; hh < NH; ++hh)
                z = fmaf(h[hh], wdc[f * NH + hh], z);
            float r = sigmoid_fast(z);
            float d = r - xc[f];
            lsum = fmaf(d, d, lsum);
        }

        // wave butterfly reduction over 64 lanes
        #pragma unroll
        for (int off = 32; off > 0; off >>= 1)
            lsum += __shfl_down(lsum, off, 64);
        if (lane == 0) wred[j][wave] = lsum;
    }

    __syncthreads();
    if (tid < CPP) {
        float s = wred[tid][0] + wred[tid][1] + wred[tid][2] + wred[tid][3];
        partials[((size_t)blockIdx.y * BX + blockIdx.x) * CPP + tid] = s;
    }
}

// Final pass: reduce partials -> per-cluster loss -> tails -> head.
__global__ __launch_bounds__(1024) void ae_final(
    const float* __restrict__ partials,  // [NPAIR][BX][CPP]
    const float* __restrict__ He,        // [HH][C]
    const float* __restrict__ hbe,       // [HH]
    const float* __restrict__ Hd,        // [C][HH]
    const float* __restrict__ hbd,       // [C]
    float* __restrict__ out)             // [0..15]=head_out, [16..31]=tails
{
    __shared__ float red[NC][65];
    __shared__ float tails_s[NC];
    __shared__ float h2_s[NHH];

    const int tid = threadIdx.x;
    const int c = tid & 15;              // cluster
    const int g = tid >> 4;              // 64 reduction groups
    const int py = c >> 1, jj = c & 1;

    float s = 0.0f;
    for (int bx = g; bx < BX; bx += 64)
        s += partials[((size_t)py * BX + bx) * CPP + jj];
    red[c][g] = s;
    __syncthreads();

    if (tid < NC) {
        float t = 0.0f;
        #pragma unroll
        for (int g2 = 0; g2 < 64; ++g2) t += red[tid][g2];
        float loss = sqrtf(t * (1.0f / 4194304.0f));   // mean over B*F
        if (loss == 0.0f) loss = 0.01f;
        tails_s[tid] = loss;
        out[16 + tid] = loss;
    }
    __syncthreads();

    if (tid < NHH) {
        float z = hbe[tid];
        #pragma unroll
        for (int cc = 0; cc < NC; ++cc)
            z = fmaf(He[tid * NC + cc], tails_s[cc], z);
        h2_s[tid] = 1.0f / (1.0f + __expf(-z));
    }
    __syncthreads();

    if (tid < NC) {
        float z = hbd[tid];
        #pragma unroll
        for (int j = 0; j < NHH; ++j)
            z = fmaf(Hd[tid * NHH + j], h2_s[j], z);
        out[tid] = 1.0f / (1.0f + __expf(-z));
    }
}

extern "C" void kernel_launch(void* const* d_in, const int* in_sizes, int n_in,
                              void* d_out, int out_size, void* d_ws, size_t ws_size,
                              hipStream_t stream) {
    // setup_inputs order: x, We, be, Wd, bd, He, hbe, Hd, hbd, cluster_idx
    const float* x   = (const float*)d_in[0];
    const float* We  = (const float*)d_in[1];
    const float* be  = (const float*)d_in[2];
    const float* Wd  = (const float*)d_in[3];
    const float* bd  = (const float*)d_in[4];
    const float* He  = (const float*)d_in[5];
    const float* hbe = (const float*)d_in[6];
    const float* Hd  = (const float*)d_in[7];
    const float* hbd = (const float*)d_in[8];
    // d_in[9] = cluster_idx: arange -> identity gather, folded in.

    float* out      = (float*)d_out;
    float* partials = (float*)d_ws;      // NPAIR*BX*CPP*4 = 64 KB

    dim3 grid(BX, NPAIR);
    ae_main<<<grid, THREADS, 0, stream>>>(x, We, be, Wd, bd, partials);
    ae_final<<<1, 1024, 0, stream>>>(partials, He, hbe, Hd, hbd, out);
}